// Round 2
// baseline (166.588 us; speedup 1.0000x reference)
//
#include <hip/hip_runtime.h>
#include <math.h>

// Problem constants (from reference setup_inputs)
#define L0      3072
#define BATCH   1024
#define NNEG    512

// -------- workspace layout (float indices into d_ws) --------
// X0 : bf16[393216]            (feat @ w_self_0, bf16)
// Y0 : bf16[393216]            = X0 + 393216 elems
// H  : float @ 393216 (3072*512)   [A,B | C,D] layer-1 inputs
// R  : float @ 1966080 (3072*256)  layer-1 output, normalized
// spPos @ 2752512, spNeg @ 2752513, rank @ 2752514 (1024 ints),
// done @ 2753538, NT @ 2753540 (float[256][512], neg_emb^T dense)

__device__ __forceinline__ float bf2f(unsigned short u) {
  return __uint_as_float(((unsigned)u) << 16);
}
__device__ __forceinline__ void store_out(float v, float* p) { *p = v; }
__device__ __forceinline__ void store_out(float v, unsigned short* p) {
  unsigned x = __float_as_uint(v);                 // f32 -> bf16 RNE
  *p = (unsigned short)((x + 0x7fff + ((x >> 16) & 1)) >> 16);
}

// Half-split matmul, 6 rows x 256 cols per 512-thread block. (unchanged)
template<int K, int AW, int HOFF, bool NORM, typename OutT>
__global__ __launch_bounds__(512) void k_mm(
    const float* __restrict__ Ain,
    const float* __restrict__ W0, const float* __restrict__ W1,
    OutT* __restrict__ Out, const int ldo, const int outHalfOff,
    float* __restrict__ zbuf, const int zcount) {
  __shared__ float AT[6 * AW];
  __shared__ float rs[8][3];
  const int t = threadIdx.x;
  if (zbuf != nullptr && blockIdx.x == 0)
    for (int z = t; z < zcount; z += 512) zbuf[z] = 0.f;
  const int base = blockIdx.x * 6;
  {
    const float4* __restrict__ src = (const float4*)(Ain + base * AW);
    float4* __restrict__ dst = (float4*)AT;
    for (int idx = t; idx < 6 * AW / 4; idx += 512) dst[idx] = src[idx];
  }
  __syncthreads();

  const int wave = t >> 6;
  const int half = wave >> 2;
  const int colg = (wave >> 1) & 1;
  const int rowg = wave & 1;
  const int rg = rowg * 3;
  const int col = colg * 64 + (t & 63);
  const float* __restrict__ W = (half ? W1 : W0) + col;
  const float* __restrict__ A0 = AT + rg * AW + half * HOFF;

  float acc[3] = {0.f, 0.f, 0.f};
#pragma unroll 4
  for (int d = 0; d < K; d += 4) {
    float4 a[3];
#pragma unroll
    for (int r = 0; r < 3; ++r) a[r] = *(const float4*)&A0[r * AW + d];
    float w[4];
#pragma unroll
    for (int i2 = 0; i2 < 4; ++i2) w[i2] = W[(d + i2) * 128];
#pragma unroll
    for (int i2 = 0; i2 < 4; ++i2)
#pragma unroll
      for (int r = 0; r < 3; ++r)
        acc[r] = fmaf(((const float*)&a[r])[i2], w[i2], acc[r]);
  }

  float scale[3] = {1.f, 1.f, 1.f};
  if (NORM) {
    float p[3];
#pragma unroll
    for (int r = 0; r < 3; ++r) p[r] = acc[r] * acc[r];
#pragma unroll
    for (int off = 32; off > 0; off >>= 1)
#pragma unroll
      for (int r = 0; r < 3; ++r) p[r] += __shfl_xor(p[r], off, 64);
    if ((t & 63) == 0) { rs[wave][0] = p[0]; rs[wave][1] = p[1]; rs[wave][2] = p[2]; }
    __syncthreads();
#pragma unroll
    for (int r = 0; r < 3; ++r) {
      const float s = rs[rowg][r] + rs[rowg + 2][r] + rs[rowg + 4][r] + rs[rowg + 6][r];
      scale[r] = rsqrtf(fmaxf(s, 1e-12f));
    }
  }
  OutT* __restrict__ O = Out + half * outHalfOff;
#pragma unroll
  for (int r = 0; r < 3; ++r)
    store_out(acc[r] * scale[r], &O[(base + rg + r) * ldo + col]);
}

// Fused layer-0 + layer-1 aggregation, bf16 gathers, ONE barrier. (unchanged)
__global__ __launch_bounds__(640) void k_aggregate(
    const unsigned short* __restrict__ X0, const unsigned short* __restrict__ Y0,
    const int* __restrict__ nb0, const int* __restrict__ nb1,
    const int* __restrict__ nb2, float* __restrict__ H) {
  __shared__ float gB[10][128], gC[10][128], gD[10][128];
  const int i = blockIdx.x;
  const int t = threadIdx.x;
  const int n0 = nb0[i];
  const int j = t >> 6;
  const int lam = t & 63;
  const int r = i * 10 + j;
  int myidx = 0;
  if (lam < 25) myidx = nb2[r * 25 + lam];
  else if (lam == 25) myidx = nb1[r];
  const int c8 = lam & 15;
  const int sub = lam >> 4;

  float d8[8];
#pragma unroll
  for (int e = 0; e < 8; ++e) d8[e] = 0.f;
#pragma unroll
  for (int m = 0; m < 7; ++m) {
    const int k = sub + 4 * m;
    const int ridx = __shfl(myidx, k, 64);
    if (k < 25) {
      const float4 raw = *(const float4*)(Y0 + ridx * 128 + c8 * 8);
      const unsigned short* u = (const unsigned short*)&raw;
#pragma unroll
      for (int e = 0; e < 8; ++e) d8[e] += bf2f(u[e]);
    }
  }
#pragma unroll
  for (int e = 0; e < 8; ++e) d8[e] += __shfl_xor(d8[e], 16, 64);
#pragma unroll
  for (int e = 0; e < 8; ++e) d8[e] += __shfl_xor(d8[e], 32, 64);

  const int r1 = __shfl(myidx, 25, 64);
  if (sub == 0) {
#pragma unroll
    for (int e = 0; e < 8; ++e) gD[j][c8 * 8 + e] = fmaxf(d8[e] * 0.04f, 0.f);
    const float4 raw = *(const float4*)(Y0 + r1 * 128 + c8 * 8);
    const unsigned short* u = (const unsigned short*)&raw;
#pragma unroll
    for (int e = 0; e < 8; ++e) gB[j][c8 * 8 + e] = bf2f(u[e]);
  } else if (sub == 1) {
    const float4 raw = *(const float4*)(X0 + r1 * 128 + c8 * 8);
    const unsigned short* u = (const unsigned short*)&raw;
#pragma unroll
    for (int e = 0; e < 8; ++e) gC[j][c8 * 8 + e] = fmaxf(bf2f(u[e]), 0.f);
  }
  __syncthreads();

  if (t < 512) {
    const int q = t >> 7, c = t & 127;
    float v;
    if (q == 0) {
      v = fmaxf(bf2f(X0[n0 * 128 + c]), 0.f);
    } else {
      const float* g = (q == 1) ? &gB[0][0] : (q == 2) ? &gC[0][0] : &gD[0][0];
      float s = 0.f;
#pragma unroll
      for (int jj = 0; jj < 10; ++jj) s += g[jj * 128 + c];
      v = s * 0.1f;
      if (q == 1) v = fmaxf(v, 0.f);
    }
    H[i * 512 + t] = v;
  }
}

__device__ __forceinline__ float softplusf(float x) {
  return fmaxf(x, 0.f) + log1pf(expf(-fabsf(x)));
}

// NT[d][c] = R[neg_idx[c]][d] — dense transposed neg embeddings (0.5 MB).
// Reads: f4 gathers (L2-hot). Writes: coalesced 256B per wave per d-row.
__global__ __launch_bounds__(256) void k_prep(
    const float* __restrict__ R, const int* __restrict__ neg_idx,
    float* __restrict__ NT) {
  const int idx = blockIdx.x * 256 + threadIdx.x;   // 128 blocks: 32768 f4 jobs
  const int c = idx & 511;
  const int d4 = idx >> 9;                          // 0..63
  const float4 v = *(const float4*)&R[neg_idx[c] * 256 + d4 * 4];
#pragma unroll
  for (int i2 = 0; i2 < 4; ++i2)
    NT[(d4 * 4 + i2) * 512 + c] = ((const float*)&v)[i2];
}

// neg_aff v3: 256 blocks (16 src x 128 neg) x 256 threads (4 waves on every
// CU). Micro-tile 2 rows x 4 contiguous cols (8 out/thread). Only S+P live in
// LDS (32 rows x 260 f32 = 33 KB), read as wave-broadcast ds_read_b128; the
// B-operand streams from dense NT via coalesced 512B wave loads (L1/L2-hot,
// no barriers, deep vmcnt pipelining). Per d4-iter/wave: 32 FMA-inst (64 cy)
// vs ~2 LDS b128 + 4 stream loads -> VALU-bound, ~1.7 us/CU floor.
// Tie semantics: acc is ONE ascending fmaf chain d=0..255; aff computed by
// lanes t<16 in the same loop, same (d4->i2) order, from staged P rows ->
// dot(S,P) bitwise == dot(S,N) whenever pos_idx==neg_idx (stable positive-
// last rank reproduction: rank = #(neg >= aff)). Finalize fused (done cnt).
__global__ __launch_bounds__(256) void k_neg(
    const float* __restrict__ O, const float* __restrict__ NT,
    const int* __restrict__ src_idx, const int* __restrict__ pos_idx,
    float* __restrict__ out_src, int* __restrict__ rank,
    float* __restrict__ spPos, float* __restrict__ spNeg,
    int* __restrict__ done) {
  __shared__ float SP[32 * 260];     // rows [0,16) src, [16,32) pos
  __shared__ float affL[16];
  __shared__ int cntL[16];
  __shared__ float wsum[4];
  __shared__ int lastDone;
  const int t = threadIdx.x;
  const int rowBase = (blockIdx.x >> 2) * 16;
  const int colBase = (blockIdx.x & 3) * 128;
  const bool first = (colBase == 0);

  if (t < 16) cntL[t] = 0;

  // stage S (16 rows) + P (16 rows), full K=256, coalesced f4 gathers
  {
    const float4* __restrict__ s4 = (const float4*)O;
#pragma unroll
    for (int idx = t; idx < 32 * 64; idx += 256) {
      const int row = idx >> 6, c4 = idx & 63;
      const int rid = (row < 16) ? src_idx[rowBase + row]
                                 : pos_idx[rowBase + row - 16];
      *(float4*)&SP[row * 260 + c4 * 4] = s4[rid * 64 + c4];
    }
  }
  if (first) {  // src_emb copy to d_out (16 rows x 64 float4)
    const float4* __restrict__ s4 = (const float4*)O;
    float4* __restrict__ d4o = (float4*)out_src;
#pragma unroll
    for (int idx = t; idx < 16 * 64; idx += 256) {
      const int rr = idx >> 6, c4 = idx & 63;
      d4o[(rowBase + rr) * 64 + c4] = s4[src_idx[rowBase + rr] * 64 + c4];
    }
  }
  __syncthreads();

  const int tc = t & 31;            // cols {4tc .. 4tc+3} within the 128
  const int tr = t >> 5;            // rows {tr, tr+8}
  const float* __restrict__ B = NT + colBase + 4 * tc;
  const float* __restrict__ A0 = SP + tr * 260;
  const float* __restrict__ A1 = SP + (tr + 8) * 260;
  const float* __restrict__ SV = SP + t * 260;          // t<16 only
  const float* __restrict__ PV = SP + (16 + t) * 260;   // t<16 only

  float acc[2][4];
#pragma unroll
  for (int r = 0; r < 2; ++r)
#pragma unroll
    for (int j = 0; j < 4; ++j) acc[r][j] = 0.f;
  float aff = 0.f;

#pragma unroll 2
  for (int d4 = 0; d4 < 64; ++d4) {
    const int dd = d4 * 4;
    const float4 a0 = *(const float4*)&A0[dd];
    const float4 a1 = *(const float4*)&A1[dd];
    float4 b[4];
#pragma unroll
    for (int i2 = 0; i2 < 4; ++i2)
      b[i2] = *(const float4*)&B[(dd + i2) * 512];
    float4 sv, pv;
    if (t < 16) {
      sv = *(const float4*)&SV[dd];
      pv = *(const float4*)&PV[dd];
    }
#pragma unroll
    for (int i2 = 0; i2 < 4; ++i2) {
      const float va0 = ((const float*)&a0)[i2];
      const float va1 = ((const float*)&a1)[i2];
#pragma unroll
      for (int j = 0; j < 4; ++j) {
        const float vb = ((const float*)&b[i2])[j];
        acc[0][j] = fmaf(va0, vb, acc[0][j]);
        acc[1][j] = fmaf(va1, vb, acc[1][j]);
      }
      if (t < 16)
        aff = fmaf(((const float*)&sv)[i2], ((const float*)&pv)[i2], aff);
    }
  }
  if (t < 16) affL[t] = aff;
  __syncthreads();

  float sp = 0.f;
  int cnt[2] = {0, 0};
#pragma unroll
  for (int r = 0; r < 2; ++r) {
    const float av = affL[tr + 8 * r];
#pragma unroll
    for (int j = 0; j < 4; ++j) {
      const float v = acc[r][j];
      sp += softplusf(v);
      cnt[r] += (v >= av) ? 1 : 0;
    }
  }
  if (cnt[0]) atomicAdd(&cntL[tr], cnt[0]);
  if (cnt[1]) atomicAdd(&cntL[tr + 8], cnt[1]);
#pragma unroll
  for (int off = 32; off > 0; off >>= 1) sp += __shfl_down(sp, off, 64);
  if ((t & 63) == 0) wsum[t >> 6] = sp;
  if (first && t < 16) atomicAdd(spPos, softplusf(-aff));
  __syncthreads();                 // cntL + wsum complete
  if (t == 0) atomicAdd(spNeg, wsum[0] + wsum[1] + wsum[2] + wsum[3]);
  if (t < 16) atomicAdd(&rank[rowBase + t], cntL[t]);

  // ---- fused finalize: last block computes mrr + loss ----
  __threadfence();
  __syncthreads();
  if (t == 0) lastDone = (atomicAdd(done, 1) == 255) ? 1 : 0;
  __syncthreads();
  if (lastDone) {
    float s = 0.f;
    for (int i = t; i < BATCH; i += 256) {
      const int rv = __hip_atomic_load(&rank[i], __ATOMIC_RELAXED,
                                       __HIP_MEMORY_SCOPE_AGENT);
      s += 1.f / (float)(rv + 1);
    }
#pragma unroll
    for (int off = 32; off > 0; off >>= 1) s += __shfl_down(s, off, 64);
    if ((t & 63) == 0) wsum[t >> 6] = s;
    __syncthreads();
    if (t == 0) {
      const float mrr = (wsum[0] + wsum[1] + wsum[2] + wsum[3]) * (1.f / 1024.f);
      const float p = __hip_atomic_load(spPos, __ATOMIC_RELAXED,
                                        __HIP_MEMORY_SCOPE_AGENT);
      const float n = __hip_atomic_load(spNeg, __ATOMIC_RELAXED,
                                        __HIP_MEMORY_SCOPE_AGENT);
      out_src[BATCH * 256]     = (p + n) * (1.f / 1024.f);
      out_src[BATCH * 256 + 1] = mrr;
    }
  }
}

extern "C" void kernel_launch(void* const* d_in, const int* in_sizes, int n_in,
                              void* d_out, int out_size, void* d_ws, size_t ws_size,
                              hipStream_t stream) {
  const float* feat   = (const float*)d_in[1];
  const int* src_idx  = (const int*)d_in[2];
  const int* pos_idx  = (const int*)d_in[3];
  const int* neg_idx  = (const int*)d_in[4];
  const int* nb0      = (const int*)d_in[5];
  const int* nb1      = (const int*)d_in[6];
  const int* nb2      = (const int*)d_in[7];
  const float* ws0    = (const float*)d_in[8];
  const float* wn0    = (const float*)d_in[9];
  const float* ws1    = (const float*)d_in[10];
  const float* wn1    = (const float*)d_in[11];

  float* wsf = (float*)d_ws;
  unsigned short* X0 = (unsigned short*)d_ws;       // bf16[393216]
  unsigned short* Y0 = X0 + 393216;                 // bf16[393216]
  float* H     = wsf + 393216;                      // 3072*512
  float* R     = wsf + 1966080;                     // 3072*256
  float* spPos = wsf + 2752512;
  float* spNeg = wsf + 2752513;
  int*   rank  = (int*)(wsf + 2752514);
  int*   done  = rank + 1024;
  float* NT    = wsf + 2753540;                     // float[256][512]
  float* out   = (float*)d_out;

  // X0 = bf16(feat@ws0), Y0 = bf16(feat@wn0); block 0 zeroes spPos/spNeg/rank/done
  k_mm<128, 128, 0, false, unsigned short><<<L0 / 6, 512, 0, stream>>>(
      feat, ws0, wn0, X0, 128, 393216, spPos, 1027);
  k_aggregate<<<L0, 640, 0, stream>>>(X0, Y0, nb0, nb1, nb2, H);
  // R[:, :128] = H[:, :256]@ws1 ; R[:, 128:] = H[:, 256:]@wn1 ; + L2-norm
  k_mm<256, 512, 256, true, float><<<L0 / 6, 512, 0, stream>>>(
      H, ws1, wn1, R, 256, 128, nullptr, 0);
  // NT = neg_emb^T dense (0.5 MB)
  k_prep<<<128, 256, 0, stream>>>(R, neg_idx, NT);
  // 256 blocks = 64 row-tiles x 4 col-tiles; finalize fused (done-counter)
  k_neg<<<256, 256, 0, stream>>>(
      R, NT, src_idx, pos_idx, out, rank, spPos, spNeg, done);
}